// Round 13
// baseline (268.433 us; speedup 1.0000x reference)
//
#include <hip/hip_runtime.h>
#include <hip/hip_bf16.h>

#define NN   8192
#define DIN  512
#define DOUT 256

typedef __attribute__((ext_vector_type(8)))  short s16x8;   // 8 bf16 (A/B frag)
typedef __attribute__((ext_vector_type(16))) float f32x16;  // 32x32 C/D frag

static __device__ __forceinline__ unsigned short f2bf(float f) {
    union { float f; unsigned u; } v; v.f = f;
    unsigned r = v.u + 0x7fffu + ((v.u >> 16) & 1u);   // RNE
    return (unsigned short)(r >> 16);
}

// ---------------- Kernel 1: FAT PREP — mask role (blocks 0-255) + wh role (256-511) --
// Roles are independent; ~1 mask block (HBM-bound) + ~1 wh block (VALU-bound) land on
// each CU -> bandwidth and compute overlap instead of serializing across launches.
// Bpk layout (verified r10-12): uint4 (ct*512 + kt)*64 + lhi*32 + l31 holds
// bf16 Wh[kt*16 + lhi*8 .. +8][ct*32 + l31] — the 32x32x16 B-fragment.
__global__ __launch_bounds__(256) void k_prep(const float* __restrict__ feat,
                                              const float* __restrict__ W,
                                              const float* __restrict__ a,
                                              const int* __restrict__ adj,
                                              uint4* __restrict__ Bpk,
                                              float* __restrict__ src,
                                              float* __restrict__ dst,
                                              unsigned char* __restrict__ bits) {
    __shared__ float lf[16 * DIN];                 // 32 KB (wh role)
    __shared__ float red[2][4][16];
    const int tid = threadIdx.x;

    if (blockIdx.x < 256) {
        // ---- mask role: 32 rows, thread = one u32 (32 cols) per row ----
        const int r0 = blockIdx.x * 32;
        #pragma unroll 4
        for (int rr = 0; rr < 32; ++rr) {
            const int row = r0 + rr;
            const int* base = adj + (size_t)row * NN + tid * 32;
            unsigned int u = 0;
            #pragma unroll
            for (int j = 0; j < 8; ++j) {
                int4 v = *(const int4*)(base + j * 4);
                unsigned int b = (v.x > 0 ? 1u : 0u) | (v.y > 0 ? 2u : 0u) |
                                 (v.z > 0 ? 4u : 0u) | (v.w > 0 ? 8u : 0u);
                u |= b << (j * 4);
            }
            *(unsigned int*)(bits + (size_t)row * 1024 + tid * 4) = u;
        }
        return;
    }

    // ---- wh role: two 16-row slices ----
    const int w = tid >> 6, lane = tid & 63;
    const int c = tid;
    for (int s = 0; s < 2; ++s) {
        const int i0 = (blockIdx.x - 256) * 32 + s * 16;
        const int kt = i0 >> 4;                    // 16-k tile index for Bpk

        const float4* fsrc = (const float4*)(feat + (size_t)i0 * DIN);
        float4* fdst = (float4*)lf;
        #pragma unroll
        for (int q = 0; q < 8; ++q) fdst[tid + q * 256] = fsrc[tid + q * 256];
        __syncthreads();

        float outs[16];
        #pragma unroll
        for (int r = 0; r < 16; ++r) outs[r] = 0.f;

        for (int k = 0; k < DIN; k += 4) {
            float w0 = W[(k + 0) * DOUT + c];
            float w1 = W[(k + 1) * DOUT + c];
            float w2 = W[(k + 2) * DOUT + c];
            float w3 = W[(k + 3) * DOUT + c];
            #pragma unroll
            for (int r = 0; r < 16; ++r) {
                float4 f = *(const float4*)&lf[r * DIN + k];   // broadcast read
                outs[r] = fmaf(f.x, w0, fmaf(f.y, w1, fmaf(f.z, w2, fmaf(f.w, w3, outs[r]))));
            }
        }

        unsigned short tb[16];
        #pragma unroll
        for (int r = 0; r < 16; ++r) tb[r] = f2bf(outs[r]);
        const int ct = c >> 5, l31c = c & 31;
        Bpk[((size_t)ct * 512 + kt) * 64 +  0 + l31c] = *(uint4*)&tb[0];
        Bpk[((size_t)ct * 512 + kt) * 64 + 32 + l31c] = *(uint4*)&tb[8];

        const float as_ = a[c], ad_ = a[DOUT + c];
        #pragma unroll
        for (int r = 0; r < 16; ++r) {
            float sv = outs[r] * as_;
            float dv = outs[r] * ad_;
            #pragma unroll
            for (int off = 32; off; off >>= 1) {
                sv += __shfl_xor(sv, off);
                dv += __shfl_xor(dv, off);
            }
            if (lane == 0) { red[0][w][r] = sv; red[1][w][r] = dv; }
        }
        __syncthreads();
        if (tid < 16)
            src[i0 + tid] = red[0][0][tid] + red[0][1][tid] + red[0][2][tid] + red[0][3][tid];
        else if (tid < 32) {
            int r = tid - 16;
            dst[i0 + r] = red[1][0][r] + red[1][1][r] + red[1][2][r] + red[1][3][r];
        }
        __syncthreads();   // red/lf safe to reuse next slice
    }
}

// ---------------- Kernel 2: masked-exp GEMM — zero barriers, reg-dbuf B --------------
// grid = 512: ks = bid&7, rt = bid>>3 (64 tiles of 128 rows). 4 independent waves:
// wv&1 = row half, wv>>1 = col half. Wave: 2 A-frags x 4 B-frags -> 8 MFMA/step.
// NEW vs r12: B(t+1) fragments prefetched into the alternate register buffer a FULL
// step early -> ~250cy L2 latency hidden under P-build+MFMA of step t.
#define AT12_STEP(Q, TT, BCUR, BNXT, M0, M1)                                             \
{                                                                                        \
    const int t_ = (TT) * 4 + (Q);                                                       \
    if (t_ < 63) {   /* prefetch B(t+1) into BNXT */                                     \
        _Pragma("unroll")                                                                \
        for (int cc = 0; cc < 4; ++cc) {                                                 \
            uint4 v_ = Bpk[((size_t)(colg * 4 + cc) * 512 + ktg0 + t_ + 1) * 64 + lane]; \
            BNXT[cc] = *(s16x8*)&v_;                                                     \
        }                                                                                \
    }                                                                                    \
    float4 d0_ = *(const float4*)(dk + t_ * 16);                                         \
    float4 d1_ = *(const float4*)(dk + t_ * 16 + 4);                                     \
    const float df_[8] = {d0_.x, d0_.y, d0_.z, d0_.w, d1_.x, d1_.y, d1_.z, d1_.w};       \
    const unsigned int m8_0 = (unsigned int)((M0) >> ((Q) * 16 + lhi8)) & 0xffu;         \
    const unsigned int m8_1 = (unsigned int)((M1) >> ((Q) * 16 + lhi8)) & 0xffu;         \
    s16x8 pa0_, pa1_;                                                                    \
    _Pragma("unroll")                                                                    \
    for (int jj = 0; jj < 8; ++jj) {                                                     \
        float x0 = si0 + df_[jj];                                                        \
        x0 = fmaxf(x0, 0.2f * x0);                        /* leaky_relu 0.2 */           \
        float p0 = (m8_0 >> jj) & 1u ? __expf(x0) : 0.f;  /* bounded: no max-sub */      \
        den0 += p0;                                                                      \
        pa0_[jj] = (short)f2bf(p0);                                                      \
        float x1 = si1 + df_[jj];                                                        \
        x1 = fmaxf(x1, 0.2f * x1);                                                       \
        float p1 = (m8_1 >> jj) & 1u ? __expf(x1) : 0.f;                                 \
        den1 += p1;                                                                      \
        pa1_[jj] = (short)f2bf(p1);                                                      \
    }                                                                                    \
    __builtin_amdgcn_s_setprio(1);                                                       \
    _Pragma("unroll")                                                                    \
    for (int cc = 0; cc < 4; ++cc) {                                                     \
        acc[0][cc] = __builtin_amdgcn_mfma_f32_32x32x16_bf16(pa0_, BCUR[cc], acc[0][cc], 0, 0, 0); \
        acc[1][cc] = __builtin_amdgcn_mfma_f32_32x32x16_bf16(pa1_, BCUR[cc], acc[1][cc], 0, 0, 0); \
    }                                                                                    \
    __builtin_amdgcn_s_setprio(0);                                                       \
}

__global__ __launch_bounds__(256, 2) void k_attn12(const unsigned char* __restrict__ bits,
                                                   const uint4* __restrict__ Bpk,
                                                   const float* __restrict__ src,
                                                   const float* __restrict__ dstg,
                                                   float* __restrict__ denp,
                                                   float* __restrict__ part) {
    const int tid  = threadIdx.x;
    const int lane = tid & 63;
    const int wv   = tid >> 6;
    const int l31  = lane & 31, lhi = lane >> 5;
    const int lhi8 = lhi * 8;
    const int rowg = wv & 1, colg = wv >> 1;

    const int ks   = blockIdx.x & 7;
    const int rt   = blockIdx.x >> 3;               // 0..63
    const int ktg0 = ks * 64;

    const int gr0 = rt * 128 + rowg * 64 + l31;     // A-frag 0 row
    const int gr1 = gr0 + 32;                       // A-frag 1 row
    const float si0 = src[gr0], si1 = src[gr1];
    const unsigned long long* bq0 =
        (const unsigned long long*)(bits + (size_t)gr0 * 1024 + ks * 128);
    const unsigned long long* bq1 =
        (const unsigned long long*)(bits + (size_t)gr1 * 1024 + ks * 128);
    const float* dk = dstg + ks * 1024 + lhi8;

    f32x16 acc[2][4];
    #pragma unroll
    for (int a = 0; a < 2; ++a)
        #pragma unroll
        for (int c = 0; c < 4; ++c)
            #pragma unroll
            for (int e = 0; e < 16; ++e) acc[a][c][e] = 0.f;
    float den0 = 0.f, den1 = 0.f;

    s16x8 bfA[4], bfB[4];
    #pragma unroll
    for (int cc = 0; cc < 4; ++cc) {                // prologue: B(0) -> bfA
        uint4 v = Bpk[((size_t)(colg * 4 + cc) * 512 + ktg0) * 64 + lane];
        bfA[cc] = *(s16x8*)&v;
    }

    for (int tt = 0; tt < 16; ++tt) {
        const unsigned long long m0 = bq0[tt];      // masks for 4 steps
        const unsigned long long m1 = bq1[tt];
        AT12_STEP(0, tt, bfA, bfB, m0, m1);         // parity: even t uses bfA
        AT12_STEP(1, tt, bfB, bfA, m0, m1);
        AT12_STEP(2, tt, bfA, bfB, m0, m1);
        AT12_STEP(3, tt, bfB, bfA, m0, m1);         // loads t+1 (mult of 4) -> bfA
    }

    den0 += __shfl_xor(den0, 32);
    den1 += __shfl_xor(den1, 32);
    if (colg == 0 && lhi == 0) {
        denp[(size_t)ks * NN + gr0] = den0;
        denp[(size_t)ks * NN + gr1] = den1;
    }

    // epilogue: C/D layout (m74/m101): col = lane&31, row = (e&3)+8*(e>>2)+4*lhi
    float* pp = part + (size_t)ks * (NN * DOUT);
    #pragma unroll
    for (int a = 0; a < 2; ++a) {
        #pragma unroll
        for (int c = 0; c < 4; ++c) {
            #pragma unroll
            for (int e = 0; e < 16; ++e) {
                const int row = rt * 128 + rowg * 64 + a * 32 + (e & 3) + 8 * (e >> 2) + 4 * lhi;
                const int col = colg * 128 + c * 32 + l31;
                pp[(size_t)row * DOUT + col] = acc[a][c][e];
            }
        }
    }
}

// ---------------- Kernel 3: out = elu( (sum_ks num) / (sum_ks den) ) -----------------
__global__ __launch_bounds__(256) void k_finish3(const float* __restrict__ part,
                                                 const float* __restrict__ denp,
                                                 float* __restrict__ out) {
    const int idx = blockIdx.x * 256 + threadIdx.x;   // float4 units
    const int row = idx >> 6;                          // 64 float4 per row
    float den = 0.f;
    #pragma unroll
    for (int i = 0; i < 8; ++i) den += denp[(size_t)i * NN + row];
    float rv = den > 0.f ? 1.f / den : 0.f;
    const size_t st = (size_t)NN * DOUT / 4;
    const float4* p = (const float4*)part;
    float sx = 0.f, sy = 0.f, sz = 0.f, sw = 0.f;
    #pragma unroll
    for (int i = 0; i < 8; ++i) {
        float4 v = p[idx + i * st];
        sx += v.x; sy += v.y; sz += v.z; sw += v.w;
    }
    float4 s;
    s.x = sx * rv; s.y = sy * rv; s.z = sz * rv; s.w = sw * rv;
    s.x = s.x > 0.f ? s.x : expm1f(s.x);
    s.y = s.y > 0.f ? s.y : expm1f(s.y);
    s.z = s.z > 0.f ? s.z : expm1f(s.z);
    s.w = s.w > 0.f ? s.w : expm1f(s.w);
    ((float4*)out)[idx] = s;
}

extern "C" void kernel_launch(void* const* d_in, const int* in_sizes, int n_in,
                              void* d_out, int out_size, void* d_ws, size_t ws_size,
                              hipStream_t stream) {
    const float* feat = (const float*)d_in[0];
    const int*   adj  = (const int*)d_in[1];
    const float* W    = (const float*)d_in[2];
    const float* a    = (const float*)d_in[3];
    float* out = (float*)d_out;

    char* ws = (char*)d_ws;
    uint4*          Bpk  = (uint4*)ws;                        // 4 MB (packed B frags)
    float*          src  = (float*)(ws + 4194304);            // 32 KB
    float*          dst  = (float*)(ws + 4227072);            // 32 KB
    float*          denp = (float*)(ws + 4259840);            // 256 KB (8 x 32 KB)
    unsigned char*  bits = (unsigned char*)(ws + 4521984);    // 8 MB
    float*          part = (float*)(ws + 12910592);           // 64 MB (8 x 8 MB)

    k_prep   <<<512,  256, 0, stream>>>(feat, W, a, adj, Bpk, src, dst, bits);
    k_attn12 <<<512,  256, 0, stream>>>(bits, Bpk, src, dst, denp, part);
    k_finish3<<<2048, 256, 0, stream>>>(part, denp, out);
}